// Round 9
// baseline (85.439 us; speedup 1.0000x reference)
//
#include <hip/hip_runtime.h>
#include <math.h>

#define DIM 4096
#define BATCH 64

typedef __attribute__((ext_vector_type(8))) short short8;
typedef __attribute__((ext_vector_type(4))) float f32x4;
typedef __attribute__((ext_vector_type(4))) unsigned int u32x4;

typedef __attribute__((address_space(3))) unsigned int lds_u32;
typedef const __attribute__((address_space(1))) unsigned int glb_u32;

__device__ __forceinline__ float4 ld4(const float* p) {
    return *reinterpret_cast<const float4*>(p);
}

// async global->LDS, 16B per lane: lane l reads g[l*16B], HW writes lds_base + l*16
__device__ __forceinline__ void gload_lds16(const float* g, float* l) {
    __builtin_amdgcn_global_load_lds((glb_u32*)g, (lds_u32*)l, 16, 0, 0);
}

// f32 -> bf16 bits, round-to-nearest-even
__device__ __forceinline__ unsigned short f2bf(float f) {
    unsigned u = __builtin_bit_cast(unsigned, f);
    u = (u + 0x7fffu + ((u >> 16) & 1u)) >> 16;
    return (unsigned short)u;
}

// pack two f32 -> one u32 of two bf16 (truncation; cheap)
__device__ __forceinline__ unsigned pack_bf2(float x, float y) {
    return (__builtin_bit_cast(unsigned, x) >> 16) |
           (__builtin_bit_cast(unsigned, y) & 0xffff0000u);
}

// K1: L2-normalize rows of input_x; emit bf16 in MFMA B-fragment order.
//   B-frag: lane l, reg j -> B[(l>>4)*8 + j][l&15]
// xb1: B for phase 1 (y = W @ xnT), K-dim = k, col = b. [bt4][kstep128][lane]xshort8
// xb2: B for phase 2 (d = (NC*y) @ xn), K-dim = b, col = j. [jt256][ks2][lane]xshort8
__global__ __launch_bounds__(256) void k_norm(const float* __restrict__ x,
                                              unsigned short* __restrict__ xb1,
                                              unsigned short* __restrict__ xb2) {
    const int b = blockIdx.x;
    const int tid = threadIdx.x;
    const float* row = x + (size_t)b * DIM;

    float ss = 0.f;
    for (int k = tid * 4; k < DIM; k += 256 * 4) {
        float4 v = ld4(row + k);
        ss += v.x * v.x + v.y * v.y + v.z * v.z + v.w * v.w;
    }
#pragma unroll
    for (int m = 32; m >= 1; m >>= 1) ss += __shfl_xor(ss, m, 64);

    __shared__ float wsum[4];
    if ((tid & 63) == 0) wsum[tid >> 6] = ss;
    __syncthreads();
    const float total = wsum[0] + wsum[1] + wsum[2] + wsum[3];
    const float scale = 1.0f / (sqrtf(total) + 1e-8f);

    const int bt = b >> 4;            // xb1 b-tile
    const int li = b & 15;            // xb1 col-in-tile
    const int ks = b >> 5;            // xb2 K-step (0/1)
    const int hi = (b & 31) >> 3;     // xb2 lane-high bits
    const int jr = b & 7;             // xb2 reg index

    for (int k = tid; k < DIM; k += 256) {
        const float v = row[k] * scale;
        const unsigned short h = f2bf(v);
        const int l1 = li | (((k & 31) >> 3) << 4);
        xb1[(size_t)((((bt * 128) + (k >> 5)) * 64 + l1) << 3) + (k & 7)] = h;
        const int l2 = (k & 15) | (hi << 4);
        xb2[(size_t)(((((k >> 4) * 2) + ks) * 64 + l2) << 3) + jr] = h;
    }
}

// Fused, linear-access version. 256 blocks x 1024 thr; block owns 16 W-rows.
// Phase 1: y = W_rows @ xnT with W staged per-1024-col super-step via
//          global_load_lds (1KB-contiguous per instruction, row-linear).
// Phase 2: per 512-col chunk: stage W,G rows to LDS (1KB instrs), MFMA d ->
//          LDS transpose, per-row coalesced epilogue (1KB-contiguous stores).
__global__ __launch_bounds__(1024) void k_fused(const float* __restrict__ W,
                                                const float* __restrict__ G,
                                                const unsigned short* __restrict__ xb1,
                                                const unsigned short* __restrict__ xb2,
                                                float* __restrict__ out) {
    // 24768 f32 = 96.75 KB, regions time-multiplexed (barrier-separated):
    //  phase 1: aw = [0,16448) [16][1028]; yp = [16448,20544); y2 = [20544,21632)
    //  phase 2: wg = [0,8256) [16][516]; gg = [8256,16512); dl = [16512,24768)
    __shared__ __align__(16) float lds[24768];
    float* aw = lds;
    float* yp = lds + 16448;
    float* y2 = lds + 20544;
    float* wg = lds;
    float* gg = lds + 8256;
    float* dl = lds + 16512;

    const int tid = threadIdx.x;
    const int wv = tid >> 6;      // wave 0..15
    const int l  = tid & 63;
    const int lr = l & 15;
    const int lh = l >> 4;
    const int i0 = blockIdx.x * 16;

    // ---------------- phase 1 ----------------
    // wave wv: b-tile bt = wv&3, K-stripe kg = wv>>2 (8 K-steps per super-step)
    const int bt = wv & 3;
    const int kg = wv >> 2;
    const short8* xb1v = (const short8*)xb1;
    f32x4 acc = {0.f, 0.f, 0.f, 0.f};

    for (int ss = 0; ss < 4; ++ss) {
        // stage W[i0..+16][ss*1024..+1024): wave wv stages its own row wv
        {
            const float* src = W + (size_t)(i0 + wv) * DIM + ss * 1024 + l * 4;
            float* dst = aw + wv * 1028;
#pragma unroll
            for (int qq = 0; qq < 4; ++qq)
                gload_lds16(src + qq * 256, dst + qq * 256);
        }
        __syncthreads();   // compiler drains vmcnt before s_barrier

#pragma unroll
        for (int i = 0; i < 8; ++i) {
            const int sl = kg * 8 + i;                 // local K-step in [0,32)
            const float* ap = aw + lr * 1028 + sl * 32 + lh * 8;
            const float4 a0 = *(const float4*)ap;
            const float4 a1 = *(const float4*)(ap + 4);
            u32x4 apk;
            apk[0] = pack_bf2(a0.x, a0.y);
            apk[1] = pack_bf2(a0.z, a0.w);
            apk[2] = pack_bf2(a1.x, a1.y);
            apk[3] = pack_bf2(a1.z, a1.w);
            const short8 af = __builtin_bit_cast(short8, apk);
            const int kstep = ss * 32 + sl;
            const short8 bf = xb1v[(size_t)bt * 8192 + kstep * 64 + l];
            acc = __builtin_amdgcn_mfma_f32_16x16x32_bf16(af, bf, acc, 0, 0, 0);
        }
        __syncthreads();   // aw fully consumed before restage
    }

    ((f32x4*)yp)[wv * 64 + l] = acc;
    __syncthreads();

    // reduce 4 K-stripe partials: thread t owns y element (r=t>>6, b=t&63)
    {
        const int r  = tid >> 6;
        const int bb = tid & 63;
        const int c  = bb & 15;
        const int btt = bb >> 4;
        const int lsrc = c | ((r >> 2) << 4);
        const int q = r & 3;
        float s = 0.f;
#pragma unroll
        for (int m = 0; m < 4; ++m)
            s += yp[(btt + 4 * m) * 256 + lsrc * 4 + q];
        y2[r * 68 + bb] = s;
    }
    __syncthreads();

    // phase-2 A-side fragments: ya = bf16((-alpha/B) * y), per lane
    const float NC = -0.01f / 64.0f;
    short8 ya0, ya1;
#pragma unroll
    for (int j = 0; j < 8; ++j) {
        ya0[j] = (short)f2bf(NC * y2[lr * 68 + lh * 8 + j]);
        ya1[j] = (short)f2bf(NC * y2[lr * 68 + 32 + lh * 8 + j]);
    }
    __syncthreads();   // y2 consumed; lds regions free for phase 2

    // ---------------- phase 2 ----------------
    const short8* xb2v = (const short8*)xb2;
    constexpr float LRc = 0.001f;

    for (int cc = 0; cc < 8; ++cc) {
        // stage W,G rows for this 512-col chunk (wave wv -> its own row wv)
        {
            const size_t rowbase = (size_t)(i0 + wv) * DIM + cc * 512 + l * 4;
            const float* srcW = W + rowbase;
            const float* srcG = G + rowbase;
            float* dstW = wg + wv * 516;
            float* dstG = gg + wv * 516;
            gload_lds16(srcW,       dstW);
            gload_lds16(srcW + 256, dstW + 256);
            gload_lds16(srcG,       dstG);
            gload_lds16(srcG + 256, dstG + 256);
        }
        // d = ya @ xb2 for wave's 2 jt tiles; transpose into dl[16][516]
#pragma unroll
        for (int t = 0; t < 2; ++t) {
            const int jl = wv * 2 + t;
            const int jt = cc * 32 + jl;
            f32x4 d = {0.f, 0.f, 0.f, 0.f};
            d = __builtin_amdgcn_mfma_f32_16x16x32_bf16(ya0, xb2v[(size_t)jt * 128 + l], d, 0, 0, 0);
            d = __builtin_amdgcn_mfma_f32_16x16x32_bf16(ya1, xb2v[(size_t)jt * 128 + 64 + l], d, 0, 0, 0);
#pragma unroll
            for (int q = 0; q < 4; ++q)
                dl[(lh * 4 + q) * 516 + jl * 16 + lr] = d[q];
        }
        __syncthreads();   // staging landed (vmcnt0) + dl visible (lgkm0)

        // epilogue: wave wv emits its own row, 2 x 1KB-contiguous stores
        {
            const size_t obase = (size_t)(i0 + wv) * DIM + cc * 512 + l * 4;
            const int lb = wv * 516 + l * 4;
#pragma unroll
            for (int h = 0; h < 2; ++h) {
                const float4 w4 = *(const float4*)(wg + lb + h * 256);
                const float4 g4 = *(const float4*)(gg + lb + h * 256);
                const float4 d4 = *(const float4*)(dl + lb + h * 256);
                float4 o;
                o.x = w4.x - LRc * g4.x + d4.x;
                o.y = w4.y - LRc * g4.y + d4.y;
                o.z = w4.z - LRc * g4.z + d4.z;
                o.w = w4.w - LRc * g4.w + d4.w;
                *(float4*)(out + obase + h * 256) = o;
            }
        }
        __syncthreads();   // wg/gg/dl consumed before next chunk restage
    }
}

extern "C" void kernel_launch(void* const* d_in, const int* in_sizes, int n_in,
                              void* d_out, int out_size, void* d_ws, size_t ws_size,
                              hipStream_t stream) {
    const float* W = (const float*)d_in[0];   // weight  (DIM x DIM)
    const float* X = (const float*)d_in[1];   // input_x (BATCH x DIM)
    const float* G = (const float*)d_in[2];   // grad    (DIM x DIM)
    float* out = (float*)d_out;

    unsigned short* xb1 = (unsigned short*)d_ws;               // 512 KB
    unsigned short* xb2 = xb1 + (size_t)DIM * BATCH;           // 512 KB

    hipLaunchKernelGGL(k_norm, dim3(BATCH), dim3(256), 0, stream, X, xb1, xb2);
    hipLaunchKernelGGL(k_fused, dim3(256), dim3(1024), 0, stream,
                       W, G, xb1, xb2, out);
}

// Round 10
// 59.978 us; speedup vs baseline: 1.4245x; 1.4245x over previous
//
#include <hip/hip_runtime.h>

#define DIM 4096
#define BATCH 64

typedef __attribute__((ext_vector_type(8))) short short8;
typedef __attribute__((ext_vector_type(4))) float f32x4;
typedef __attribute__((ext_vector_type(4))) unsigned int u32x4;

typedef __attribute__((address_space(3))) unsigned int lds_u32;
typedef const __attribute__((address_space(1))) unsigned int glb_u32;

__device__ __forceinline__ float4 ld4(const float* p) {
    return *reinterpret_cast<const float4*>(p);
}
__device__ __forceinline__ void gload_lds16(const float* g, float* l) {
    __builtin_amdgcn_global_load_lds((glb_u32*)g, (lds_u32*)l, 16, 0, 0);
}
// f32 -> bf16 bits, round-to-nearest-even
__device__ __forceinline__ unsigned short f2bf(float f) {
    unsigned u = __builtin_bit_cast(unsigned, f);
    u = (u + 0x7fffu + ((u >> 16) & 1u)) >> 16;
    return (unsigned short)u;
}
// pack two f32 -> one u32 of two bf16 (truncation)
__device__ __forceinline__ unsigned pack_bf2(float x, float y) {
    return (__builtin_bit_cast(unsigned, x) >> 16) |
           (__builtin_bit_cast(unsigned, y) & 0xffff0000u);
}

#define SCHED() __builtin_amdgcn_sched_barrier(0)
#define WAITV_(N) asm volatile("s_waitcnt vmcnt(" #N ")" ::: "memory")
#define WAITV(N) do { WAITV_(N); SCHED(); } while (0)
#define WAITL()  do { asm volatile("s_waitcnt lgkmcnt(0)" ::: "memory"); SCHED(); } while (0)
#define SBAR()   do { __builtin_amdgcn_s_barrier(); SCHED(); } while (0)

// K1: L2-normalize rows of input_x; emit bf16 in MFMA B-fragment order.
//   B-frag: lane l, reg j -> B[(l>>4)*8 + j][l&15]
// xb1: B for phase 1 (y = W @ xnT), K-dim = k, col = b. [bt4][kstep128][lane]xshort8
// xb2: B for phase 2 (d = (NC*y) @ xn), K-dim = b, col = j. [jt256][ks2][lane]xshort8
__global__ __launch_bounds__(256) void k_norm(const float* __restrict__ x,
                                              unsigned short* __restrict__ xb1,
                                              unsigned short* __restrict__ xb2) {
    const int b = blockIdx.x;
    const int tid = threadIdx.x;
    const float* row = x + (size_t)b * DIM;

    float ss = 0.f;
    for (int k = tid * 4; k < DIM; k += 256 * 4) {
        float4 v = ld4(row + k);
        ss += v.x * v.x + v.y * v.y + v.z * v.z + v.w * v.w;
    }
#pragma unroll
    for (int m = 32; m >= 1; m >>= 1) ss += __shfl_xor(ss, m, 64);

    __shared__ float wsum[4];
    if ((tid & 63) == 0) wsum[tid >> 6] = ss;
    __syncthreads();
    const float total = wsum[0] + wsum[1] + wsum[2] + wsum[3];
    const float scale = 1.0f / (sqrtf(total) + 1e-8f);

    const int bt = b >> 4;
    const int li = b & 15;
    const int ks = b >> 5;
    const int hi = (b & 31) >> 3;
    const int jr = b & 7;

    for (int k = tid; k < DIM; k += 256) {
        const float v = row[k] * scale;
        const unsigned short h = f2bf(v);
        const int l1 = li | (((k & 31) >> 3) << 4);
        xb1[(size_t)((((bt * 128) + (k >> 5)) * 64 + l1) << 3) + (k & 7)] = h;
        const int l2 = (k & 15) | (hi << 4);
        xb2[(size_t)(((((k >> 4) * 2) + ks) * 64 + l2) << 3) + jr] = h;
    }
}

// Fused kernel, depth-2 counted-vmcnt pipeline (guide T3/T4).
// Block = 16 W-rows, 16 waves. Phase 1: y = W_rows @ xnT with W staged through
// 3 LDS buffers, 512 cols/step, staging issued 2 steps ahead, raw s_barrier +
// literal vmcnt(N) (never 0 mid-loop). Phase 2: same pipeline for W,G rows in
// 256-col chunks; MFMA d-tiles -> LDS transpose -> coalesced 1KB row stores.
__global__ __launch_bounds__(1024, 4) void k_fused(const float* __restrict__ W,
                                                   const float* __restrict__ G,
                                                   const unsigned short* __restrict__ xb1,
                                                   const unsigned short* __restrict__ xb2,
                                                   float* __restrict__ out) {
    // f32 layout (time-multiplexed, barrier-separated):
    //  phase 1: aw[3] @ 0/8192/16384 (16 rows x 512), yp @ 24576, y2 @ 28672
    //  phase 2: wgg[3] @ 0/8192/16384 (W:+0, G:+4096), dl @ 24576 (16 x 260)
    __shared__ __align__(16) float lds[29760];

    const int tid = threadIdx.x;
    const int wv = tid >> 6;
    const int l  = tid & 63;
    const int lr = l & 15;
    const int lh = l >> 4;
    const int i0 = blockIdx.x * 16;
    const short8* xb1v = (const short8*)xb1;
    const short8* xb2v = (const short8*)xb2;

    // ---------------- phase 1 ----------------
    const int bt = wv & 3;          // b-tile this wave accumulates
    const int kg = wv >> 2;         // K-stripe within the 512-col step
    const int key  = wv & 7;        // XOR swizzle key when staging own row wv
    const int rkey = lr & 7;        // XOR key when reading row lr
    f32x4 acc = {0.f, 0.f, 0.f, 0.f};
    short8 fA0, fA1, fA2, fA3, fB0, fB1, fB2, fB3;

    // B-fragment prefetch: 4 K-steps for step SS (stride 64 short8 per kstep)
#define LOADF(SS, F0_, F1_, F2_, F3_) do { \
    const short8* p_ = xb1v + bt * 8192 + ((SS) * 16 + kg * 4) * 64 + l; \
    F0_ = p_[0]; F1_ = p_[64]; F2_ = p_[128]; F3_ = p_[192]; SCHED(); } while (0)

    // Stage own row wv, 512 f32 = 128x16B chunks, source pre-XOR-swizzled so
    // linear DMA lands a swizzled layout (reader applies same XOR).
#define STAGE1(SS, B_) do { \
    const float* s_ = W + (size_t)(i0 + wv) * DIM + (SS) * 512; \
    float* d_ = lds + (B_) * 8192 + wv * 512; \
    gload_lds16(s_ + ((l ^ key) << 2), d_); \
    gload_lds16(s_ + ((64 + (l ^ key)) << 2), d_ + 256); SCHED(); } while (0)

#define MFMA1(B_, I_, FF_) do { \
    const int c0_ = (kg * 4 + (I_)) * 8 + lh * 2; \
    const f32x4 a0_ = *(const f32x4*)(lds + (B_) * 8192 + lr * 512 + ((c0_ ^ rkey) << 2)); \
    const f32x4 a1_ = *(const f32x4*)(lds + (B_) * 8192 + lr * 512 + (((c0_ + 1) ^ rkey) << 2)); \
    u32x4 ap_; \
    ap_[0] = pack_bf2(a0_[0], a0_[1]); ap_[1] = pack_bf2(a0_[2], a0_[3]); \
    ap_[2] = pack_bf2(a1_[0], a1_[1]); ap_[3] = pack_bf2(a1_[2], a1_[3]); \
    acc = __builtin_amdgcn_mfma_f32_16x16x32_bf16(__builtin_bit_cast(short8, ap_), FF_, acc, 0, 0, 0); \
  } while (0)

#define P1_MFMA(B_, F0_, F1_, F2_, F3_) do { \
    MFMA1(B_, 0, F0_); MFMA1(B_, 1, F1_); MFMA1(B_, 2, F2_); MFMA1(B_, 3, F3_); } while (0)

#define P1_STEP(SS_, NW_, BC_, BN_, FC0,FC1,FC2,FC3, FN0,FN1,FN2,FN3) do { \
    WAITV(NW_); SBAR(); \
    LOADF((SS_) + 1, FN0, FN1, FN2, FN3); \
    STAGE1((SS_) + 2, BN_); \
    P1_MFMA(BC_, FC0, FC1, FC2, FC3); } while (0)

    LOADF(0, fA0, fA1, fA2, fA3);
    STAGE1(0, 0);
    STAGE1(1, 1);
    P1_STEP(0, 2, 0, 2, fA0,fA1,fA2,fA3, fB0,fB1,fB2,fB3);
    P1_STEP(1, 6, 1, 0, fB0,fB1,fB2,fB3, fA0,fA1,fA2,fA3);
    P1_STEP(2, 6, 2, 1, fA0,fA1,fA2,fA3, fB0,fB1,fB2,fB3);
    P1_STEP(3, 6, 0, 2, fB0,fB1,fB2,fB3, fA0,fA1,fA2,fA3);
    P1_STEP(4, 6, 1, 0, fA0,fA1,fA2,fA3, fB0,fB1,fB2,fB3);
    P1_STEP(5, 6, 2, 1, fB0,fB1,fB2,fB3, fA0,fA1,fA2,fA3);
    // ss = 6 (no stage 8)
    WAITV(6); SBAR();
    LOADF(7, fB0, fB1, fB2, fB3);
    P1_MFMA(0, fA0, fA1, fA2, fA3);
    // ss = 7
    WAITV(4); SBAR();
    P1_MFMA(1, fB0, fB1, fB2, fB3);

    // store per-wave partial, reduce over the 4 K-stripes (drain is fine here)
    ((f32x4*)(lds + 24576))[wv * 64 + l] = acc;
    __syncthreads();
    {
        const int r  = tid >> 6;
        const int bb = tid & 63;
        const int btt = bb >> 4;
        const int lii = (bb & 15) | ((r >> 2) << 4);
        const int jq  = r & 3;
        float s = 0.f;
#pragma unroll
        for (int g = 0; g < 4; ++g)
            s += lds[24576 + ((g * 4 + btt) * 64 + lii) * 4 + jq];
        lds[28672 + r * 68 + bb] = s;
    }
    __syncthreads();

    const float NC = -0.01f / 64.0f;
    short8 ya0, ya1;
#pragma unroll
    for (int j = 0; j < 8; ++j) {
        ya0[j] = (short)f2bf(NC * lds[28672 + lr * 68 + lh * 8 + j]);
        ya1[j] = (short)f2bf(NC * lds[28672 + lr * 68 + 32 + lh * 8 + j]);
    }
    __syncthreads();

    // ---------------- phase 2 ----------------
    constexpr float LRc = 0.001f;
    short8 xA0, xA1, xB0, xB1;

#define LOADX(C_, X0_, X1_) do { \
    const short8* p_ = xb2v + ((C_) * 16 + wv) * 128 + l; \
    X0_ = p_[0]; X1_ = p_[64]; SCHED(); } while (0)

#define STAGE2(C_, B_) do { \
    const size_t rb_ = (size_t)(i0 + wv) * DIM + (C_) * 256 + (l << 2); \
    gload_lds16(W + rb_, lds + (B_) * 8192 + wv * 256); \
    gload_lds16(G + rb_, lds + (B_) * 8192 + 4096 + wv * 256); SCHED(); } while (0)

#define P2_MFMA(X0_, X1_) do { \
    f32x4 d_ = {0.f, 0.f, 0.f, 0.f}; \
    d_ = __builtin_amdgcn_mfma_f32_16x16x32_bf16(ya0, X0_, d_, 0, 0, 0); \
    d_ = __builtin_amdgcn_mfma_f32_16x16x32_bf16(ya1, X1_, d_, 0, 0, 0); \
    lds[24576 + (lh * 4 + 0) * 260 + wv * 16 + lr] = d_[0]; \
    lds[24576 + (lh * 4 + 1) * 260 + wv * 16 + lr] = d_[1]; \
    lds[24576 + (lh * 4 + 2) * 260 + wv * 16 + lr] = d_[2]; \
    lds[24576 + (lh * 4 + 3) * 260 + wv * 16 + lr] = d_[3]; } while (0)

#define P2_EPI(C_, B_) do { \
    const f32x4 w_ = *(const f32x4*)(lds + (B_) * 8192 + wv * 256 + (l << 2)); \
    const f32x4 g_ = *(const f32x4*)(lds + (B_) * 8192 + 4096 + wv * 256 + (l << 2)); \
    const f32x4 dd_ = *(const f32x4*)(lds + 24576 + wv * 260 + (l << 2)); \
    f32x4 o_; \
    o_[0] = w_[0] - LRc * g_[0] + dd_[0]; \
    o_[1] = w_[1] - LRc * g_[1] + dd_[1]; \
    o_[2] = w_[2] - LRc * g_[2] + dd_[2]; \
    o_[3] = w_[3] - LRc * g_[3] + dd_[3]; \
    *(f32x4*)(out + (size_t)(i0 + wv) * DIM + (C_) * 256 + (l << 2)) = o_; } while (0)

#define P2_STEP(C_, NW_, BC_, BN_, XC0_, XC1_, XN0_, XN1_) do { \
    WAITV(NW_); SBAR(); \
    LOADX((C_) + 1, XN0_, XN1_); \
    STAGE2((C_) + 2, BN_); \
    P2_MFMA(XC0_, XC1_); \
    WAITL(); SBAR(); \
    P2_EPI(C_, BC_); } while (0)

    LOADX(0, xA0, xA1);
    STAGE2(0, 0);
    STAGE2(1, 1);
    P2_STEP(0,  2, 0, 2, xA0, xA1, xB0, xB1);
    P2_STEP(1,  4, 1, 0, xB0, xB1, xA0, xA1);
    P2_STEP(2,  4, 2, 1, xA0, xA1, xB0, xB1);
    P2_STEP(3,  4, 0, 2, xB0, xB1, xA0, xA1);
    P2_STEP(4,  4, 1, 0, xA0, xA1, xB0, xB1);
    P2_STEP(5,  4, 2, 1, xB0, xB1, xA0, xA1);
    P2_STEP(6,  4, 0, 2, xA0, xA1, xB0, xB1);
    P2_STEP(7,  4, 1, 0, xB0, xB1, xA0, xA1);
    P2_STEP(8,  4, 2, 1, xA0, xA1, xB0, xB1);
    P2_STEP(9,  4, 0, 2, xB0, xB1, xA0, xA1);
    P2_STEP(10, 4, 1, 0, xA0, xA1, xB0, xB1);
    P2_STEP(11, 4, 2, 1, xB0, xB1, xA0, xA1);
    P2_STEP(12, 4, 0, 2, xA0, xA1, xB0, xB1);
    P2_STEP(13, 4, 1, 0, xB0, xB1, xA0, xA1);
    // c = 14 (no stage 16)
    WAITV(4); SBAR();
    LOADX(15, xB0, xB1);
    P2_MFMA(xA0, xA1);
    WAITL(); SBAR();
    P2_EPI(14, 2);
    // c = 15
    WAITV(2); SBAR();
    P2_MFMA(xB0, xB1);
    WAITL(); SBAR();
    P2_EPI(15, 0);
}

extern "C" void kernel_launch(void* const* d_in, const int* in_sizes, int n_in,
                              void* d_out, int out_size, void* d_ws, size_t ws_size,
                              hipStream_t stream) {
    const float* W = (const float*)d_in[0];   // weight  (DIM x DIM)
    const float* X = (const float*)d_in[1];   // input_x (BATCH x DIM)
    const float* G = (const float*)d_in[2];   // grad    (DIM x DIM)
    float* out = (float*)d_out;

    unsigned short* xb1 = (unsigned short*)d_ws;               // 512 KB
    unsigned short* xb2 = xb1 + (size_t)DIM * BATCH;           // 512 KB

    hipLaunchKernelGGL(k_norm, dim3(BATCH), dim3(256), 0, stream, X, xb1, xb2);
    hipLaunchKernelGGL(k_fused, dim3(DIM / 16), dim3(1024), 0, stream,
                       W, G, xb1, xb2, out);
}